// Round 9
// baseline (560.918 us; speedup 1.0000x reference)
//
#include <hip/hip_runtime.h>
#include <hip/hip_bf16.h>

// Problem constants: B=16, T=8192, M=P=128, N2=128. Chunks: 64 per batch, L=128.
#define LCH 128
#define NCH 64
#define GRID 512       // persistent grid; 2 rounds of 512 chunks (batches 0-7, then 8-15)

typedef __attribute__((ext_vector_type(8))) short short8v;
typedef __attribute__((ext_vector_type(4))) short short4v;
typedef __attribute__((ext_vector_type(4))) float f32x4;

// ws layout (float2 offsets)
#define W2_LDINV 0          // [128 r][128 n]  Ld^{-(r+1)}
#define W2_LDP   16384      // [128 r][128 n]  Ld^{r+1}
#define W2_E     32768      // [1024 g][128 n]
#define W2_LDLP  163840     // [64 k][128 n]   Ldl^k = Ld^{128k}
#define W2_CNT   172032     // 16 uint arrival counters (one per batch)
#define WS_WPACK_BYTE  (589824 * 4)         // 32768 bf16 (64 KB): [ntile16][ks4][lane64][j8]
#define WS_CCPACK_BYTE (589824 * 4 + 65536) // 32768 bf16: [ptile8][ks8][lane64][j8]

// bus LDS layout (k-blocked): byte(s, n') = (s>>3)*4096 + n'*16 + (s&7)*2
#define BUS_BYTE(s, np) ((((s) >> 3) * 4096) + ((np) * 16) + (((s) & 7) * 2))

__device__ inline unsigned short f2bf(float f) {
    union { __hip_bfloat16 h; unsigned short u; } v;
    v.h = __float2bfloat16(f);
    return v.u;
}
__device__ inline short4v pack4(float a, float b, float c, float d) {
    union { __hip_bfloat162 h2[2]; short4v s4; } pk;
    pk.h2[0] = __float22bfloat162_rn(make_float2(a, b));
    pk.h2[1] = __float22bfloat162_rn(make_float2(c, d));
    return pk.s4;
}

// cross-XCD-coherent 8-byte data movement (agent-scope atomics; R8-validated).
__device__ inline void coh_store_f2(float2* p, float2 v) {
    union { float2 f; unsigned long long u; } pk; pk.f = v;
    __hip_atomic_store((unsigned long long*)p, pk.u, __ATOMIC_RELAXED,
                       __HIP_MEMORY_SCOPE_AGENT);
}
__device__ inline float2 coh_load_f2(const float2* p) {
    union { float2 f; unsigned long long u; } pk;
    pk.u = __hip_atomic_load((const unsigned long long*)p, __ATOMIC_RELAXED,
                             __HIP_MEMORY_SCOPE_AGENT);
    return pk.f;
}

// ---------------- k0a: power tables (f64 exact) + counter reset ----------------
__global__ void k0_pows(const float* __restrict__ lp, const float* __restrict__ delta,
                        float2* __restrict__ ws2) {
    const int r = blockIdx.x;
    const int tid = threadIdx.x;
    const int n = tid & 127;
    const double d = (double)delta[0];
    const double lre = -exp((double)lp[n]);
    const double lim = (double)lp[128 + n];
    if (r < 128) {
        const double kk = (double)(r + 1) * d;
        if (tid < 128) {
            const double mag = exp(-lre * kk);
            ws2[W2_LDINV + r * 128 + n] = make_float2((float)(mag * cos(lim * kk)),
                                                      (float)(-mag * sin(lim * kk)));
        } else {
            const double mag = exp(lre * kk);
            ws2[W2_LDP + r * 128 + n] = make_float2((float)(mag * cos(lim * kk)),
                                                    (float)(mag * sin(lim * kk)));
        }
    } else {
        if (tid < 128) {
            const int k = r - 128;                       // 0..63
            const double kk = (double)k * d * (double)LCH;
            const double mag = exp(lre * kk);
            ws2[W2_LDLP + k * 128 + n] = make_float2((float)(mag * cos(lim * kk)),
                                                     (float)(mag * sin(lim * kk)));
        } else if (r == 128 && tid < 144) {
            __hip_atomic_store(&((unsigned*)(ws2 + W2_CNT))[tid - 128], 0u,
                               __ATOMIC_RELAXED, __HIP_MEMORY_SCOPE_AGENT);
        }
    }
}

// ---------------- k0b: pack W = Bd^T as B-fragments ----------------
__global__ void k0_wpack(const float* __restrict__ lp, const float* __restrict__ bp,
                         const float* __restrict__ delta, unsigned short* __restrict__ wpack) {
    const int gid = blockIdx.x * 512 + threadIdx.x;    // 0..32767
    const int j = gid & 7;
    const int lane = (gid >> 3) & 63;
    const int ks = (gid >> 9) & 3;
    const int ntile = gid >> 11;
    const int np = ntile * 16 + (lane & 15);
    const int m = ks * 32 + ((lane >> 4) & 3) * 8 + j;
    const int n = np & 127;
    const double d = (double)delta[0];
    const double lre = -exp((double)lp[n]);
    const double lim = (double)lp[128 + n];
    const double er = exp(lre * d);
    const double ldr = er * cos(lim * d), ldi = er * sin(lim * d);
    const double nr = ldr - 1.0, ni = ldi;
    const double den = lre * lre + lim * lim;
    const double cr = (nr * lre + ni * lim) / den;
    const double ci = (ni * lre - nr * lim) / den;
    const double br = (double)bp[n * 128 + m];
    const double bi = (double)bp[16384 + n * 128 + m];
    const double v = (np < 128) ? (cr * br - ci * bi) : (cr * bi + ci * br);
    wpack[gid] = f2bf((float)v);
}

// ---------------- k0c: pack CC (K=256, re/im interleaved along k) ----------------
__global__ void k0_cpack(const float* __restrict__ cp, unsigned short* __restrict__ ccpack) {
    const int gid = blockIdx.x * 512 + threadIdx.x;    // 0..32767
    const int j = gid & 7;
    const int lane = (gid >> 3) & 63;
    const int ks = (gid >> 9) & 7;
    const int ptile = gid >> 12;
    const int p = ptile * 16 + (lane & 15);
    const int k = ks * 32 + ((lane >> 4) & 3) * 8 + j;
    const int n = k >> 1;
    const float v = ((k & 1) == 0) ? 2.0f * cp[p * 128 + n] : -2.0f * cp[16384 + p * 128 + n];
    ccpack[gid] = f2bf(v);
}

// ================= fused persistent kernel (MONOLITHIC — no array-passing helpers;
// R8's helper refactor put z[8][2] in scratch: 376/403 MB FETCH/WRITE. R4's monolithic
// body ran the identical phases spill-free at 64 VGPR + 64 AGPR.) =================
__global__ __launch_bounds__(512, 4) void kmain(const float* __restrict__ u,
                                                float2* __restrict__ ws2,
                                                const unsigned short* __restrict__ wpack,
                                                const unsigned short* __restrict__ ccpack,
                                                float* __restrict__ y) {
    __shared__ unsigned short lds[32768];     // 64 KB
    const int tid = threadIdx.x;
    const int lane = tid & 63;
    const int w = tid >> 6;
    const int tl = lane & 15;
    const int gq = (lane >> 4) & 3;
    const int n = w * 16 + tl;
    unsigned* cnt = (unsigned*)(ws2 + W2_CNT);
    const short8v* wp = (const short8v*)wpack;
    const short8v* cc8 = (const short8v*)ccpack;

    for (int rd = 0; rd < 2; ++rd) {
        const int g = rd * GRID + (int)blockIdx.x;
        const int b = g >> 6;
        const int c = g & 63;

        if (rd) __syncthreads();       // previous round's GEMM3 LDS reads retired

        // ---- stage u chunk -> LDS bf16 [t][m], XOR swizzle ----
        {
            const float4* uf = (const float4*)(u + (size_t)(b * 8192 + c * 128) * 128);
#pragma unroll
            for (int it = 0; it < 8; ++it) {
                const int f4 = it * 512 + tid;
                const float4 v = uf[f4];
                const int t = f4 >> 5;
                const int m = (f4 & 31) * 4;
                const int byte = (t * 256 + m * 2) ^ ((t & 7) << 4);
                *(short4v*)((char*)lds + byte) = pack4(v.x, v.y, v.z, v.w);
            }
        }
        __syncthreads();

        // ---- GEMM1 + Ldinv scale + bus write, two halves: h=1 (s>=64) first ----
#pragma unroll
        for (int hh = 0; hh < 2; ++hh) {
            const int h = 1 - hh;
            f32x4 acc[4][2];
#pragma unroll
            for (int i = 0; i < 4; ++i) { acc[i][0] = (f32x4)0.f; acc[i][1] = (f32x4)0.f; }
            __builtin_amdgcn_s_setprio(1);
#pragma unroll
            for (int ks = 0; ks < 4; ++ks) {
                const short8v b0 = wp[(w * 4 + ks) * 64 + lane];
                const short8v b1 = wp[((8 + w) * 4 + ks) * 64 + lane];
#pragma unroll
                for (int tt2 = 0; tt2 < 4; ++tt2) {
                    const int t = (h * 4 + tt2) * 16 + tl;
                    const int byte = (t * 256 + (ks * 32 + gq * 8) * 2) ^ ((t & 7) << 4);
                    const short8v a = *(const short8v*)((const char*)lds + byte);
                    acc[tt2][0] = __builtin_amdgcn_mfma_f32_16x16x32_bf16(a, b0, acc[tt2][0], 0, 0, 0);
                    acc[tt2][1] = __builtin_amdgcn_mfma_f32_16x16x32_bf16(a, b1, acc[tt2][1], 0, 0, 0);
                }
            }
            __builtin_amdgcn_s_setprio(0);
            __builtin_amdgcn_sched_barrier(0);
            if (h == 0) __syncthreads();   // all waves done reading u; s<64 bus may overwrite it
#pragma unroll
            for (int tt2 = 0; tt2 < 4; ++tt2) {
                float vr[4], vi[4];
#pragma unroll
                for (int reg = 0; reg < 4; ++reg) {
                    const int r = (h * 4 + tt2) * 16 + gq * 4 + reg;
                    const float2 li = ws2[W2_LDINV + r * 128 + n];
                    const float br = acc[tt2][0][reg], bi = acc[tt2][1][reg];
                    vr[reg] = li.x * br - li.y * bi;
                    vi[reg] = li.x * bi + li.y * br;
                }
                const int s0 = (h * 4 + tt2) * 16 + gq * 4;
                const int rowr = w * 16 + tl;
                const int rowi = 128 + rowr;
                *(short4v*)((char*)lds + BUS_BYTE(s0, rowr)) = pack4(vr[0], vr[1], vr[2], vr[3]);
                *(short4v*)((char*)lds + BUS_BYTE(s0, rowi)) = pack4(vi[0], vi[1], vi[2], vi[3]);
            }
            __builtin_amdgcn_sched_barrier(0);
        }

        // ---- GEMM2: z = T_lower_ones x Bus (wave-private rows; no barrier needed) ----
        short8v ONES, D0, D1;
#pragma unroll
        for (int j = 0; j < 8; ++j) {
            const int sl = gq * 8 + j;
            ONES[j] = (short)0x3F80;
            D0[j] = (sl <= tl) ? (short)0x3F80 : (short)0;
            D1[j] = (sl <= tl + 16) ? (short)0x3F80 : (short)0;
        }
        f32x4 z[8][2];
#pragma unroll
        for (int i = 0; i < 8; ++i) { z[i][0] = (f32x4)0.f; z[i][1] = (f32x4)0.f; }
#pragma unroll
        for (int ks = 0; ks < 4; ++ks) {
            const int sb = ks * 32 + gq * 8;                 // frag k-base, (sb&7)==0
            const int rowr = w * 16 + tl;
            const int rowi = 128 + rowr;
            const short8v b0 = *(const short8v*)((const char*)lds + BUS_BYTE(sb, rowr));
            const short8v b1 = *(const short8v*)((const char*)lds + BUS_BYTE(sb, rowi));
#pragma unroll
            for (int tt = 0; tt < 8; ++tt) {
                if (tt < 2 * ks) continue;                   // zero block
                const short8v a = (tt == 2 * ks) ? D0 : ((tt == 2 * ks + 1) ? D1 : ONES);
                z[tt][0] = __builtin_amdgcn_mfma_f32_16x16x32_bf16(a, b0, z[tt][0], 0, 0, 0);
                z[tt][1] = __builtin_amdgcn_mfma_f32_16x16x32_bf16(a, b1, z[tt][1], 0, 0, 0);
            }
        }

        // ---- publish E[g][n] = Ld^128 * z[127][n] (row 127 = z[7][*][3], lanes gq==3) ----
        if (gq == 3) {
            const float er = z[7][0][3], ei = z[7][1][3];
            const float2 ld = ws2[W2_LDP + 127 * 128 + n];
            coh_store_f2(&ws2[W2_E + g * 128 + n],
                         make_float2(ld.x * er - ld.y * ei, ld.x * ei + ld.y * er));
        }
        __syncthreads();               // all waves' E stores drained (vmcnt0 at barrier)
        if (tid == 0) {
            __hip_atomic_fetch_add(&cnt[b], 1u, __ATOMIC_RELEASE, __HIP_MEMORY_SCOPE_AGENT);
        }

        // ---- carry[c] = sum_{j<c} Ldl^(c-1-j) * E[b*64+j] ----
        float cr = 0.f, ci = 0.f;
        if (c > 0) {
            if (tid == 0) {
                while (__hip_atomic_load(&cnt[b], __ATOMIC_ACQUIRE,
                                         __HIP_MEMORY_SCOPE_AGENT) < (unsigned)NCH) {
                    __builtin_amdgcn_s_sleep(2);
                }
            }
            __syncthreads();
            for (int j = 0; j < c; ++j) {
                const float2 e = coh_load_f2(&ws2[W2_E + (b * NCH + j) * 128 + n]);
                const float2 pw = ws2[W2_LDLP + (c - 1 - j) * 128 + n];
                cr += pw.x * e.x - pw.y * e.y;
                ci += pw.x * e.y + pw.y * e.x;
            }
        }

        // ---- x[t][k''] = Ldp[t] (.) (z + carry), re/im interleaved along k'' ----
#pragma unroll
        for (int tt = 0; tt < 8; ++tt) {
#pragma unroll
            for (int reg = 0; reg < 4; ++reg) {
                const int r = tt * 16 + gq * 4 + reg;
                const float2 ld = ws2[W2_LDP + r * 128 + n];
                const float zr = z[tt][0][reg] + cr;
                const float zi = z[tt][1][reg] + ci;
                const float xr = ld.x * zr - ld.y * zi;
                const float xi = ld.x * zi + ld.y * zr;
                union { __hip_bfloat162 h2; unsigned uu; } pk;
                pk.h2 = __float22bfloat162_rn(make_float2(xr, xi));
                const int byte = (r * 512 + n * 4) ^ ((r & 7) << 4);
                *(unsigned*)((char*)lds + byte) = pk.uu;
            }
        }
        __syncthreads();

        // ---- GEMM3: y[t][p]; wave w owns p-tile w, all t ----
        f32x4 yac[8];
#pragma unroll
        for (int i = 0; i < 8; ++i) yac[i] = (f32x4)0.f;
        __builtin_amdgcn_s_setprio(1);
#pragma unroll
        for (int ks = 0; ks < 8; ++ks) {
            const short8v bfrg = cc8[(w * 8 + ks) * 64 + lane];
#pragma unroll
            for (int tt = 0; tt < 8; ++tt) {
                const int t = tt * 16 + tl;
                const int byte = (t * 512 + (ks * 32 + gq * 8) * 2) ^ ((t & 7) << 4);
                const short8v a = *(const short8v*)((const char*)lds + byte);
                yac[tt] = __builtin_amdgcn_mfma_f32_16x16x32_bf16(a, bfrg, yac[tt], 0, 0, 0);
            }
        }
        __builtin_amdgcn_s_setprio(0);
        const int p = w * 16 + tl;
        float* yrow = y + (size_t)(b * 8192 + c * 128) * 128;
#pragma unroll
        for (int tt = 0; tt < 8; ++tt) {
#pragma unroll
            for (int reg = 0; reg < 4; ++reg) {
                const int t = tt * 16 + gq * 4 + reg;
                yrow[t * 128 + p] = yac[tt][reg];
            }
        }
    }
}

extern "C" void kernel_launch(void* const* d_in, const int* in_sizes, int n_in,
                              void* d_out, int out_size, void* d_ws, size_t ws_size,
                              hipStream_t stream) {
    const float* u     = (const float*)d_in[0];
    const float* lp    = (const float*)d_in[1];
    const float* bp    = (const float*)d_in[2];
    const float* cp    = (const float*)d_in[3];
    const float* delta = (const float*)d_in[4];
    float* y  = (float*)d_out;
    float2* ws2 = (float2*)d_ws;
    unsigned short* wpack  = (unsigned short*)((char*)d_ws + WS_WPACK_BYTE);
    unsigned short* ccpack = (unsigned short*)((char*)d_ws + WS_CCPACK_BYTE);

    k0_pows <<<192, 256, 0, stream>>>(lp, delta, ws2);
    k0_wpack<<<64, 512, 0, stream>>>(lp, bp, delta, wpack);
    k0_cpack<<<64, 512, 0, stream>>>(cp, ccpack);
    kmain   <<<GRID, 512, 0, stream>>>(u, ws2, wpack, ccpack, y);
}

// Round 10
// 147.813 us; speedup vs baseline: 3.7948x; 3.7948x over previous
//
#include <hip/hip_runtime.h>
#include <hip/hip_bf16.h>

// Problem constants: B=16, T=8192, M=P=128, N2=128. Chunks: 64 per batch, L=128.
// Fused persistent kernel launched TWICE (gbase = 0, 512): no outer loop in the
// kernel body — an outer loop makes LICM hoist ~70 VGPRs of loop-invariant MFMA
// fragments across the 64-AGPR z accumulator, overflowing the 128-reg budget and
// spilling ~1.3 KB/thread (R5/R6/R8/R9 all showed this; loop-free R4 did not).
#define LCH 128
#define NCH 64
#define GRID 512       // blocks per launch; 2 blocks/CU x 256 CU -> whole grid co-resident

typedef __attribute__((ext_vector_type(8))) short short8v;
typedef __attribute__((ext_vector_type(4))) short short4v;
typedef __attribute__((ext_vector_type(4))) float f32x4;

// ws layout (float2 offsets)
#define W2_LDINV 0          // [128 r][128 n]  Ld^{-(r+1)}
#define W2_LDP   16384      // [128 r][128 n]  Ld^{r+1}
#define W2_E     32768      // [1024 g][128 n]
#define W2_LDLP  163840     // [64 k][128 n]   Ldl^k = Ld^{128k}
#define W2_CNT   172032     // 16 uint arrival counters (one per batch)
#define WS_WPACK_BYTE  (589824 * 4)         // 32768 bf16 (64 KB): [ntile16][ks4][lane64][j8]
#define WS_CCPACK_BYTE (589824 * 4 + 65536) // 32768 bf16: [ptile8][ks8][lane64][j8]

// bus LDS layout (k-blocked): byte(s, n') = (s>>3)*4096 + n'*16 + (s&7)*2
#define BUS_BYTE(s, np) ((((s) >> 3) * 4096) + ((np) * 16) + (((s) & 7) * 2))

__device__ inline unsigned short f2bf(float f) {
    union { __hip_bfloat16 h; unsigned short u; } v;
    v.h = __float2bfloat16(f);
    return v.u;
}
__device__ inline short4v pack4(float a, float b, float c, float d) {
    union { __hip_bfloat162 h2[2]; short4v s4; } pk;
    pk.h2[0] = __float22bfloat162_rn(make_float2(a, b));
    pk.h2[1] = __float22bfloat162_rn(make_float2(c, d));
    return pk.s4;
}

// cross-XCD-coherent 8-byte data movement (agent-scope atomics; R8-validated).
__device__ inline void coh_store_f2(float2* p, float2 v) {
    union { float2 f; unsigned long long u; } pk; pk.f = v;
    __hip_atomic_store((unsigned long long*)p, pk.u, __ATOMIC_RELAXED,
                       __HIP_MEMORY_SCOPE_AGENT);
}
__device__ inline float2 coh_load_f2(const float2* p) {
    union { float2 f; unsigned long long u; } pk;
    pk.u = __hip_atomic_load((const unsigned long long*)p, __ATOMIC_RELAXED,
                             __HIP_MEMORY_SCOPE_AGENT);
    return pk.f;
}

// ---------------- k0a: power tables (f64 exact) + counter reset ----------------
__global__ void k0_pows(const float* __restrict__ lp, const float* __restrict__ delta,
                        float2* __restrict__ ws2) {
    const int r = blockIdx.x;
    const int tid = threadIdx.x;
    const int n = tid & 127;
    const double d = (double)delta[0];
    const double lre = -exp((double)lp[n]);
    const double lim = (double)lp[128 + n];
    if (r < 128) {
        const double kk = (double)(r + 1) * d;
        if (tid < 128) {
            const double mag = exp(-lre * kk);
            ws2[W2_LDINV + r * 128 + n] = make_float2((float)(mag * cos(lim * kk)),
                                                      (float)(-mag * sin(lim * kk)));
        } else {
            const double mag = exp(lre * kk);
            ws2[W2_LDP + r * 128 + n] = make_float2((float)(mag * cos(lim * kk)),
                                                    (float)(mag * sin(lim * kk)));
        }
    } else {
        if (tid < 128) {
            const int k = r - 128;                       // 0..63
            const double kk = (double)k * d * (double)LCH;
            const double mag = exp(lre * kk);
            ws2[W2_LDLP + k * 128 + n] = make_float2((float)(mag * cos(lim * kk)),
                                                     (float)(mag * sin(lim * kk)));
        } else if (r == 128 && tid < 144) {
            __hip_atomic_store(&((unsigned*)(ws2 + W2_CNT))[tid - 128], 0u,
                               __ATOMIC_RELAXED, __HIP_MEMORY_SCOPE_AGENT);
        }
    }
}

// ---------------- k0b: pack W = Bd^T as B-fragments ----------------
__global__ void k0_wpack(const float* __restrict__ lp, const float* __restrict__ bp,
                         const float* __restrict__ delta, unsigned short* __restrict__ wpack) {
    const int gid = blockIdx.x * 512 + threadIdx.x;    // 0..32767
    const int j = gid & 7;
    const int lane = (gid >> 3) & 63;
    const int ks = (gid >> 9) & 3;
    const int ntile = gid >> 11;
    const int np = ntile * 16 + (lane & 15);
    const int m = ks * 32 + ((lane >> 4) & 3) * 8 + j;
    const int n = np & 127;
    const double d = (double)delta[0];
    const double lre = -exp((double)lp[n]);
    const double lim = (double)lp[128 + n];
    const double er = exp(lre * d);
    const double ldr = er * cos(lim * d), ldi = er * sin(lim * d);
    const double nr = ldr - 1.0, ni = ldi;
    const double den = lre * lre + lim * lim;
    const double cr = (nr * lre + ni * lim) / den;
    const double ci = (ni * lre - nr * lim) / den;
    const double br = (double)bp[n * 128 + m];
    const double bi = (double)bp[16384 + n * 128 + m];
    const double v = (np < 128) ? (cr * br - ci * bi) : (cr * bi + ci * br);
    wpack[gid] = f2bf((float)v);
}

// ---------------- k0c: pack CC (K=256, re/im interleaved along k) ----------------
__global__ void k0_cpack(const float* __restrict__ cp, unsigned short* __restrict__ ccpack) {
    const int gid = blockIdx.x * 512 + threadIdx.x;    // 0..32767
    const int j = gid & 7;
    const int lane = (gid >> 3) & 63;
    const int ks = (gid >> 9) & 7;
    const int ptile = gid >> 12;
    const int p = ptile * 16 + (lane & 15);
    const int k = ks * 32 + ((lane >> 4) & 3) * 8 + j;
    const int n = k >> 1;
    const float v = ((k & 1) == 0) ? 2.0f * cp[p * 128 + n] : -2.0f * cp[16384 + p * 128 + n];
    ccpack[gid] = f2bf(v);
}

// ================= fused kernel, ONE chunk per block, launched twice =================
__global__ __launch_bounds__(512, 4) void kmain(const float* __restrict__ u,
                                                float2* __restrict__ ws2,
                                                const unsigned short* __restrict__ wpack,
                                                const unsigned short* __restrict__ ccpack,
                                                float* __restrict__ y,
                                                int gbase) {
    __shared__ unsigned short lds[32768];     // 64 KB
    const int tid = threadIdx.x;
    const int lane = tid & 63;
    const int w = tid >> 6;
    const int tl = lane & 15;
    const int gq = (lane >> 4) & 3;
    const int n = w * 16 + tl;
    unsigned* cnt = (unsigned*)(ws2 + W2_CNT);
    const short8v* wp = (const short8v*)wpack;
    const short8v* cc8 = (const short8v*)ccpack;

    const int g = gbase + (int)blockIdx.x;
    const int b = g >> 6;
    const int c = g & 63;

    // ---- stage u chunk -> LDS bf16 [t][m], XOR swizzle ----
    {
        const float4* uf = (const float4*)(u + (size_t)(b * 8192 + c * 128) * 128);
#pragma unroll
        for (int it = 0; it < 8; ++it) {
            const int f4 = it * 512 + tid;
            const float4 v = uf[f4];
            const int t = f4 >> 5;
            const int m = (f4 & 31) * 4;
            const int byte = (t * 256 + m * 2) ^ ((t & 7) << 4);
            *(short4v*)((char*)lds + byte) = pack4(v.x, v.y, v.z, v.w);
        }
    }
    __syncthreads();

    // ---- GEMM1 + Ldinv scale + bus write, two halves: h=1 (s>=64) first ----
#pragma unroll
    for (int hh = 0; hh < 2; ++hh) {
        const int h = 1 - hh;
        f32x4 acc[4][2];
#pragma unroll
        for (int i = 0; i < 4; ++i) { acc[i][0] = (f32x4)0.f; acc[i][1] = (f32x4)0.f; }
        __builtin_amdgcn_s_setprio(1);
#pragma unroll
        for (int ks = 0; ks < 4; ++ks) {
            const short8v b0 = wp[(w * 4 + ks) * 64 + lane];
            const short8v b1 = wp[((8 + w) * 4 + ks) * 64 + lane];
#pragma unroll
            for (int tt2 = 0; tt2 < 4; ++tt2) {
                const int t = (h * 4 + tt2) * 16 + tl;
                const int byte = (t * 256 + (ks * 32 + gq * 8) * 2) ^ ((t & 7) << 4);
                const short8v a = *(const short8v*)((const char*)lds + byte);
                acc[tt2][0] = __builtin_amdgcn_mfma_f32_16x16x32_bf16(a, b0, acc[tt2][0], 0, 0, 0);
                acc[tt2][1] = __builtin_amdgcn_mfma_f32_16x16x32_bf16(a, b1, acc[tt2][1], 0, 0, 0);
            }
        }
        __builtin_amdgcn_s_setprio(0);
        __builtin_amdgcn_sched_barrier(0);
        if (h == 0) __syncthreads();   // all waves done reading u; s<64 bus may overwrite it
#pragma unroll
        for (int tt2 = 0; tt2 < 4; ++tt2) {
            float vr[4], vi[4];
#pragma unroll
            for (int reg = 0; reg < 4; ++reg) {
                const int r = (h * 4 + tt2) * 16 + gq * 4 + reg;
                const float2 li = ws2[W2_LDINV + r * 128 + n];
                const float br = acc[tt2][0][reg], bi = acc[tt2][1][reg];
                vr[reg] = li.x * br - li.y * bi;
                vi[reg] = li.x * bi + li.y * br;
            }
            const int s0 = (h * 4 + tt2) * 16 + gq * 4;
            const int rowr = w * 16 + tl;
            const int rowi = 128 + rowr;
            *(short4v*)((char*)lds + BUS_BYTE(s0, rowr)) = pack4(vr[0], vr[1], vr[2], vr[3]);
            *(short4v*)((char*)lds + BUS_BYTE(s0, rowi)) = pack4(vi[0], vi[1], vi[2], vi[3]);
        }
        __builtin_amdgcn_sched_barrier(0);
    }

    // ---- GEMM2: z = T_lower_ones x Bus (wave-private rows; no barrier needed) ----
    short8v ONES, D0, D1;
#pragma unroll
    for (int j = 0; j < 8; ++j) {
        const int sl = gq * 8 + j;
        ONES[j] = (short)0x3F80;
        D0[j] = (sl <= tl) ? (short)0x3F80 : (short)0;
        D1[j] = (sl <= tl + 16) ? (short)0x3F80 : (short)0;
    }
    f32x4 z[8][2];
#pragma unroll
    for (int i = 0; i < 8; ++i) { z[i][0] = (f32x4)0.f; z[i][1] = (f32x4)0.f; }
#pragma unroll
    for (int ks = 0; ks < 4; ++ks) {
        const int sb = ks * 32 + gq * 8;                 // frag k-base, (sb&7)==0
        const int rowr = w * 16 + tl;
        const int rowi = 128 + rowr;
        const short8v b0 = *(const short8v*)((const char*)lds + BUS_BYTE(sb, rowr));
        const short8v b1 = *(const short8v*)((const char*)lds + BUS_BYTE(sb, rowi));
#pragma unroll
        for (int tt = 0; tt < 8; ++tt) {
            if (tt < 2 * ks) continue;                   // zero block
            const short8v a = (tt == 2 * ks) ? D0 : ((tt == 2 * ks + 1) ? D1 : ONES);
            z[tt][0] = __builtin_amdgcn_mfma_f32_16x16x32_bf16(a, b0, z[tt][0], 0, 0, 0);
            z[tt][1] = __builtin_amdgcn_mfma_f32_16x16x32_bf16(a, b1, z[tt][1], 0, 0, 0);
        }
    }

    // ---- publish E[g][n] = Ld^128 * z[127][n] (row 127 = z[7][*][3], lanes gq==3) ----
    if (gq == 3) {
        const float er = z[7][0][3], ei = z[7][1][3];
        const float2 ld = ws2[W2_LDP + 127 * 128 + n];
        coh_store_f2(&ws2[W2_E + g * 128 + n],
                     make_float2(ld.x * er - ld.y * ei, ld.x * ei + ld.y * er));
    }
    __syncthreads();               // all waves' E stores drained (vmcnt0 at barrier)
    if (tid == 0) {
        __hip_atomic_fetch_add(&cnt[b], 1u, __ATOMIC_RELEASE, __HIP_MEMORY_SCOPE_AGENT);
    }

    // ---- carry[c] = sum_{j<c} Ldl^(c-1-j) * E[b*64+j] ----
    float cr = 0.f, ci = 0.f;
    if (c > 0) {
        if (tid == 0) {
            while (__hip_atomic_load(&cnt[b], __ATOMIC_ACQUIRE,
                                     __HIP_MEMORY_SCOPE_AGENT) < (unsigned)NCH) {
                __builtin_amdgcn_s_sleep(2);
            }
        }
        __syncthreads();
        for (int j = 0; j < c; ++j) {
            const float2 e = coh_load_f2(&ws2[W2_E + (b * NCH + j) * 128 + n]);
            const float2 pw = ws2[W2_LDLP + (c - 1 - j) * 128 + n];
            cr += pw.x * e.x - pw.y * e.y;
            ci += pw.x * e.y + pw.y * e.x;
        }
    }

    // ---- x[t][k''] = Ldp[t] (.) (z + carry), re/im interleaved along k'' ----
#pragma unroll
    for (int tt = 0; tt < 8; ++tt) {
#pragma unroll
        for (int reg = 0; reg < 4; ++reg) {
            const int r = tt * 16 + gq * 4 + reg;
            const float2 ld = ws2[W2_LDP + r * 128 + n];
            const float zr = z[tt][0][reg] + cr;
            const float zi = z[tt][1][reg] + ci;
            const float xr = ld.x * zr - ld.y * zi;
            const float xi = ld.x * zi + ld.y * zr;
            union { __hip_bfloat162 h2; unsigned uu; } pk;
            pk.h2 = __float22bfloat162_rn(make_float2(xr, xi));
            const int byte = (r * 512 + n * 4) ^ ((r & 7) << 4);
            *(unsigned*)((char*)lds + byte) = pk.uu;
        }
    }
    __syncthreads();

    // ---- GEMM3: y[t][p]; wave w owns p-tile w, all t ----
    f32x4 yac[8];
#pragma unroll
    for (int i = 0; i < 8; ++i) yac[i] = (f32x4)0.f;
    __builtin_amdgcn_s_setprio(1);
#pragma unroll
    for (int ks = 0; ks < 8; ++ks) {
        const short8v bfrg = cc8[(w * 8 + ks) * 64 + lane];
#pragma unroll
        for (int tt = 0; tt < 8; ++tt) {
            const int t = tt * 16 + tl;
            const int byte = (t * 512 + (ks * 32 + gq * 8) * 2) ^ ((t & 7) << 4);
            const short8v a = *(const short8v*)((const char*)lds + byte);
            yac[tt] = __builtin_amdgcn_mfma_f32_16x16x32_bf16(a, bfrg, yac[tt], 0, 0, 0);
        }
    }
    __builtin_amdgcn_s_setprio(0);
    const int p = w * 16 + tl;
    float* yrow = y + (size_t)(b * 8192 + c * 128) * 128;
#pragma unroll
    for (int tt = 0; tt < 8; ++tt) {
#pragma unroll
        for (int reg = 0; reg < 4; ++reg) {
            const int t = tt * 16 + gq * 4 + reg;
            yrow[t * 128 + p] = yac[tt][reg];
        }
    }
}

extern "C" void kernel_launch(void* const* d_in, const int* in_sizes, int n_in,
                              void* d_out, int out_size, void* d_ws, size_t ws_size,
                              hipStream_t stream) {
    const float* u     = (const float*)d_in[0];
    const float* lp    = (const float*)d_in[1];
    const float* bp    = (const float*)d_in[2];
    const float* cp    = (const float*)d_in[3];
    const float* delta = (const float*)d_in[4];
    float* y  = (float*)d_out;
    float2* ws2 = (float2*)d_ws;
    unsigned short* wpack  = (unsigned short*)((char*)d_ws + WS_WPACK_BYTE);
    unsigned short* ccpack = (unsigned short*)((char*)d_ws + WS_CCPACK_BYTE);

    k0_pows <<<192, 256, 0, stream>>>(lp, delta, ws2);
    k0_wpack<<<64, 512, 0, stream>>>(lp, bp, delta, wpack);
    k0_cpack<<<64, 512, 0, stream>>>(cp, ccpack);
    kmain   <<<GRID, 512, 0, stream>>>(u, ws2, wpack, ccpack, y, 0);      // batches 0-7
    kmain   <<<GRID, 512, 0, stream>>>(u, ws2, wpack, ccpack, y, GRID);   // batches 8-15
}

// Round 11
// 97.852 us; speedup vs baseline: 5.7323x; 1.5106x over previous
//
#include <hip/hip_runtime.h>
#include <hip/hip_bf16.h>

// Problem constants: B=16, T=8192, M=P=128, N2=128.
// Chunks: L=64 -> 128 chunks/batch, 2048 total. Three-kernel structure (R4-proven);
// fusion via grid-sync abandoned (R5-R10: spill + spin/atomic-load tax > k1 savings).
#define LCH 64
#define NCH 128
#define NCHUNKS 2048

typedef __attribute__((ext_vector_type(8))) short short8v;
typedef __attribute__((ext_vector_type(4))) short short4v;
typedef __attribute__((ext_vector_type(4))) float f32x4;

// ws layout (float2 offsets). E is transformed IN-PLACE into CIN by k2 -> total
// float2 region 2.23 MB, packs keep the R4-proven byte offsets (2.36 MB+).
#define W2_LDINV 0          // [64 r][128 n]  Ld^{-(r+1)}
#define W2_LDP   8192       // [64 r][128 n]  Ld^{r+1}
#define W2_E     16384      // [2048 g][128 n]  (E, then CIN in-place)
#define WS_WPACK_BYTE  2359296              // 32768 bf16: [ntile16][ks4][lane64][j8]
#define WS_CCPACK_BYTE (2359296 + 65536)    // 32768 bf16: [ptile8][ks8][lane64][j8]

// bus LDS layout (k-blocked): byte(s, n') = (s>>3)*4096 + n'*16 + (s&7)*2 ; s in [0,64)
#define BUS_BYTE(s, np) ((((s) >> 3) * 4096) + ((np) * 16) + (((s) & 7) * 2))

__device__ inline unsigned short f2bf(float f) {
    union { __hip_bfloat16 h; unsigned short u; } v;
    v.h = __float2bfloat16(f);
    return v.u;
}
__device__ inline short4v pack4(float a, float b, float c, float d) {
    union { __hip_bfloat162 h2[2]; short4v s4; } pk;
    pk.h2[0] = __float22bfloat162_rn(make_float2(a, b));
    pk.h2[1] = __float22bfloat162_rn(make_float2(c, d));
    return pk.s4;
}

// ---------------- k0: all setup in one launch ----------------
// blocks 0..63: power tables (f64 exact); 64..127: wpack; 128..191: ccpack.
__global__ void k0_all(const float* __restrict__ lp, const float* __restrict__ bp,
                       const float* __restrict__ cp, const float* __restrict__ delta,
                       float2* __restrict__ ws2, unsigned short* __restrict__ wpack,
                       unsigned short* __restrict__ ccpack) {
    const int r = blockIdx.x;
    const int tid = threadIdx.x;
    if (r < 64) {
        if (tid < 256) {
            const int n = tid & 127;
            const double d = (double)delta[0];
            const double lre = -exp((double)lp[n]);
            const double lim = (double)lp[128 + n];
            const double kk = (double)(r + 1) * d;
            if (tid < 128) {            // Ldinv[r][n] = exp(-Lam*(r+1)d)
                const double mag = exp(-lre * kk);
                ws2[W2_LDINV + r * 128 + n] = make_float2((float)(mag * cos(lim * kk)),
                                                          (float)(-mag * sin(lim * kk)));
            } else {                    // Ldp[r][n] = exp(+Lam*(r+1)d)
                const double mag = exp(lre * kk);
                ws2[W2_LDP + r * 128 + n] = make_float2((float)(mag * cos(lim * kk)),
                                                        (float)(mag * sin(lim * kk)));
            }
        }
    } else if (r < 128) {
        // wpack: W[m, n'] ; n'<128 -> Re(Bd[n'][m]), else Im. frag (ntile,ks,lane,j).
        const int gid = (r - 64) * 512 + tid;          // 0..32767
        const int j = gid & 7;
        const int lane = (gid >> 3) & 63;
        const int ks = (gid >> 9) & 3;
        const int ntile = gid >> 11;
        const int np = ntile * 16 + (lane & 15);
        const int m = ks * 32 + ((lane >> 4) & 3) * 8 + j;
        const int n = np & 127;
        const double d = (double)delta[0];
        const double lre = -exp((double)lp[n]);
        const double lim = (double)lp[128 + n];
        const double er = exp(lre * d);
        const double ldr = er * cos(lim * d), ldi = er * sin(lim * d);
        const double nr = ldr - 1.0, ni = ldi;
        const double den = lre * lre + lim * lim;
        const double cr = (nr * lre + ni * lim) / den;
        const double ci = (ni * lre - nr * lim) / den;
        const double br = (double)bp[n * 128 + m];
        const double bi = (double)bp[16384 + n * 128 + m];
        const double v = (np < 128) ? (cr * br - ci * bi) : (cr * bi + ci * br);
        wpack[gid] = f2bf((float)v);
    } else {
        // ccpack: CC[k=2n+0,p] = 2*C_re[p][n] ; CC[k=2n+1,p] = -2*C_im[p][n]
        const int gid = (r - 128) * 512 + tid;         // 0..32767
        const int j = gid & 7;
        const int lane = (gid >> 3) & 63;
        const int ks = (gid >> 9) & 7;
        const int ptile = gid >> 12;
        const int p = ptile * 16 + (lane & 15);
        const int k = ks * 32 + ((lane >> 4) & 3) * 8 + j;
        const int n = k >> 1;
        const float v = ((k & 1) == 0) ? 2.0f * cp[p * 128 + n]
                                       : -2.0f * cp[16384 + p * 128 + n];
        ccpack[gid] = f2bf(v);
    }
}

// ---------------- k1: chunk end-states E (zero-init local scan) ----------------
__global__ __launch_bounds__(512, 6) void k1_end(const float* __restrict__ u,
                                                 float2* __restrict__ ws2,
                                                 const unsigned short* __restrict__ wpack) {
    __shared__ unsigned short lds_u[8192];    // 16 KB: [64 t][128 m] bf16, XOR swizzle
    const int tid = threadIdx.x;
    const int lane = tid & 63;
    const int w = tid >> 6;
    const int tl = lane & 15;
    const int gq = (lane >> 4) & 3;
    const int g = blockIdx.x;
    const int b = g >> 7;
    const int c = g & 127;
    const int n = w * 16 + tl;
    const short8v* wp = (const short8v*)wpack;

    {   // stage: 64x128 f32 = 2048 float4, 4 per thread
        const float4* uf = (const float4*)(u + (size_t)(b * 8192 + c * LCH) * 128);
#pragma unroll
        for (int it = 0; it < 4; ++it) {
            const int f4 = it * 512 + tid;
            const float4 v = uf[f4];
            const int t = f4 >> 5;
            const int m = (f4 & 31) * 4;
            const int byte = (t * 256 + m * 2) ^ ((t & 7) << 4);
            *(short4v*)((char*)lds_u + byte) = pack4(v.x, v.y, v.z, v.w);
        }
    }
    __syncthreads();

    f32x4 acc[4][2];
#pragma unroll
    for (int i = 0; i < 4; ++i) { acc[i][0] = (f32x4)0.f; acc[i][1] = (f32x4)0.f; }
    __builtin_amdgcn_s_setprio(1);
#pragma unroll
    for (int ks = 0; ks < 4; ++ks) {
        const short8v b0 = wp[(w * 4 + ks) * 64 + lane];
        const short8v b1 = wp[((8 + w) * 4 + ks) * 64 + lane];
#pragma unroll
        for (int tt = 0; tt < 4; ++tt) {
            const int t = tt * 16 + tl;
            const int byte = (t * 256 + (ks * 32 + gq * 8) * 2) ^ ((t & 7) << 4);
            const short8v a = *(const short8v*)((const char*)lds_u + byte);
            acc[tt][0] = __builtin_amdgcn_mfma_f32_16x16x32_bf16(a, b0, acc[tt][0], 0, 0, 0);
            acc[tt][1] = __builtin_amdgcn_mfma_f32_16x16x32_bf16(a, b1, acc[tt][1], 0, 0, 0);
        }
    }
    __builtin_amdgcn_s_setprio(0);

    // E[n] = Ld^64 * sum_r Ldinv[r] (.) Bu[r,n]
    float er = 0.f, ei = 0.f;
#pragma unroll
    for (int tt = 0; tt < 4; ++tt) {
#pragma unroll
        for (int reg = 0; reg < 4; ++reg) {
            const int r = tt * 16 + gq * 4 + reg;
            const float2 li = ws2[W2_LDINV + r * 128 + n];
            const float br = acc[tt][0][reg], bi = acc[tt][1][reg];
            er += li.x * br - li.y * bi;
            ei += li.x * bi + li.y * br;
        }
    }
    er += __shfl_xor(er, 16); ei += __shfl_xor(ei, 16);
    er += __shfl_xor(er, 32); ei += __shfl_xor(ei, 32);
    const float2 ld = ws2[W2_LDP + 63 * 128 + n];
    if (lane < 16) {
        ws2[W2_E + g * 128 + n] = make_float2(ld.x * er - ld.y * ei,
                                              ld.x * ei + ld.y * er);
    }
}

// ---------------- k2: chunk-level scan; E -> CIN in-place ----------------
__global__ void k2_carry(float2* __restrict__ ws2) {
    const int idx = blockIdx.x * 256 + threadIdx.x;   // 0..2047 = (b,n)
    const int b = idx >> 7;
    const int n = idx & 127;
    const float2 l = ws2[W2_LDP + 63 * 128 + n];      // Ld^64
    float cr = 0.f, ci = 0.f;
    for (int c = 0; c < NCH; ++c) {
        const int o = (b * NCH + c) * 128 + n;
        const float2 e = ws2[W2_E + o];
        ws2[W2_E + o] = make_float2(cr, ci);          // CIN[c] = carry before chunk c
        const float nr = fmaf(l.x, cr, fmaf(-l.y, ci, e.x));
        const float ni = fmaf(l.x, ci, fmaf(l.y, cr, e.y));
        cr = nr; ci = ni;
    }
}

// ---------------- k3: stage -> GEMM1 -> bus -> tri-cumsum -> x -> GEMM3 ----------------
// LDS 32 KB: u [0,16K) dies after GEMM1; bus s>=32 half -> [16K,32K) (no alias),
// s<32 half -> [0,16K) after the barrier; x overwrites all after GEMM2.
__global__ __launch_bounds__(512, 6) void k3_main(const float* __restrict__ u,
                                                  const float2* __restrict__ ws2,
                                                  const unsigned short* __restrict__ wpack,
                                                  const unsigned short* __restrict__ ccpack,
                                                  float* __restrict__ y) {
    __shared__ unsigned short lds[16384];     // 32 KB
    const int tid = threadIdx.x;
    const int lane = tid & 63;
    const int w = tid >> 6;
    const int tl = lane & 15;
    const int gq = (lane >> 4) & 3;
    const int g = blockIdx.x;
    const int b = g >> 7;
    const int c = g & 127;
    const int n = w * 16 + tl;
    const short8v* wp = (const short8v*)wpack;
    const short8v* cc8 = (const short8v*)ccpack;

    {   // stage u chunk -> LDS bf16 [t][m], XOR swizzle
        const float4* uf = (const float4*)(u + (size_t)(b * 8192 + c * LCH) * 128);
#pragma unroll
        for (int it = 0; it < 4; ++it) {
            const int f4 = it * 512 + tid;
            const float4 v = uf[f4];
            const int t = f4 >> 5;
            const int m = (f4 & 31) * 4;
            const int byte = (t * 256 + m * 2) ^ ((t & 7) << 4);
            *(short4v*)((char*)lds + byte) = pack4(v.x, v.y, v.z, v.w);
        }
    }
    __syncthreads();

    // GEMM1 (single pass: acc[4][2] = 32 AGPR)
    f32x4 acc[4][2];
#pragma unroll
    for (int i = 0; i < 4; ++i) { acc[i][0] = (f32x4)0.f; acc[i][1] = (f32x4)0.f; }
    __builtin_amdgcn_s_setprio(1);
#pragma unroll
    for (int ks = 0; ks < 4; ++ks) {
        const short8v b0 = wp[(w * 4 + ks) * 64 + lane];
        const short8v b1 = wp[((8 + w) * 4 + ks) * 64 + lane];
#pragma unroll
        for (int tt = 0; tt < 4; ++tt) {
            const int t = tt * 16 + tl;
            const int byte = (t * 256 + (ks * 32 + gq * 8) * 2) ^ ((t & 7) << 4);
            const short8v a = *(const short8v*)((const char*)lds + byte);
            acc[tt][0] = __builtin_amdgcn_mfma_f32_16x16x32_bf16(a, b0, acc[tt][0], 0, 0, 0);
            acc[tt][1] = __builtin_amdgcn_mfma_f32_16x16x32_bf16(a, b1, acc[tt][1], 0, 0, 0);
        }
    }
    __builtin_amdgcn_s_setprio(0);
    __builtin_amdgcn_sched_barrier(0);

    // Ldinv scale + bus write: tt=2,3 (s>=32 -> bytes [16K,32K), disjoint from u) first
#pragma unroll
    for (int tt = 2; tt < 4; ++tt) {
        float vr[4], vi[4];
#pragma unroll
        for (int reg = 0; reg < 4; ++reg) {
            const int r = tt * 16 + gq * 4 + reg;
            const float2 li = ws2[W2_LDINV + r * 128 + n];
            const float br = acc[tt][0][reg], bi = acc[tt][1][reg];
            vr[reg] = li.x * br - li.y * bi;
            vi[reg] = li.x * bi + li.y * br;
        }
        const int s0 = tt * 16 + gq * 4;
        const int rowr = w * 16 + tl;
        const int rowi = 128 + rowr;
        *(short4v*)((char*)lds + BUS_BYTE(s0, rowr)) = pack4(vr[0], vr[1], vr[2], vr[3]);
        *(short4v*)((char*)lds + BUS_BYTE(s0, rowi)) = pack4(vi[0], vi[1], vi[2], vi[3]);
    }
    __syncthreads();    // all waves finished GEMM1 u-reads; s<32 bus may overwrite u
#pragma unroll
    for (int tt = 0; tt < 2; ++tt) {
        float vr[4], vi[4];
#pragma unroll
        for (int reg = 0; reg < 4; ++reg) {
            const int r = tt * 16 + gq * 4 + reg;
            const float2 li = ws2[W2_LDINV + r * 128 + n];
            const float br = acc[tt][0][reg], bi = acc[tt][1][reg];
            vr[reg] = li.x * br - li.y * bi;
            vi[reg] = li.x * bi + li.y * br;
        }
        const int s0 = tt * 16 + gq * 4;
        const int rowr = w * 16 + tl;
        const int rowi = 128 + rowr;
        *(short4v*)((char*)lds + BUS_BYTE(s0, rowr)) = pack4(vr[0], vr[1], vr[2], vr[3]);
        *(short4v*)((char*)lds + BUS_BYTE(s0, rowi)) = pack4(vi[0], vi[1], vi[2], vi[3]);
    }
    __builtin_amdgcn_sched_barrier(0);

    // GEMM2: z = T_lower_ones x Bus  (wave-private rows; no barrier needed)
    short8v ONES, D0, D1;
#pragma unroll
    for (int j = 0; j < 8; ++j) {
        const int sl = gq * 8 + j;
        ONES[j] = (short)0x3F80;
        D0[j] = (sl <= tl) ? (short)0x3F80 : (short)0;
        D1[j] = (sl <= tl + 16) ? (short)0x3F80 : (short)0;
    }
    f32x4 z[4][2];
#pragma unroll
    for (int i = 0; i < 4; ++i) { z[i][0] = (f32x4)0.f; z[i][1] = (f32x4)0.f; }
#pragma unroll
    for (int ks = 0; ks < 2; ++ks) {
        const int sb = ks * 32 + gq * 8;
        const int rowr = w * 16 + tl;
        const int rowi = 128 + rowr;
        const short8v b0 = *(const short8v*)((const char*)lds + BUS_BYTE(sb, rowr));
        const short8v b1 = *(const short8v*)((const char*)lds + BUS_BYTE(sb, rowi));
#pragma unroll
        for (int tt = 0; tt < 4; ++tt) {
            if (tt < 2 * ks) continue;                   // zero block
            const short8v a = (tt == 2 * ks) ? D0 : ((tt == 2 * ks + 1) ? D1 : ONES);
            z[tt][0] = __builtin_amdgcn_mfma_f32_16x16x32_bf16(a, b0, z[tt][0], 0, 0, 0);
            z[tt][1] = __builtin_amdgcn_mfma_f32_16x16x32_bf16(a, b1, z[tt][1], 0, 0, 0);
        }
    }
    __syncthreads();    // all waves done reading bus (x overwrites below)

    // x[t][k''] = Ldp[t] (.) (z + carry); carry = CIN (k2 wrote it into E slot)
    const float2 cin = ws2[W2_E + g * 128 + n];
#pragma unroll
    for (int tt = 0; tt < 4; ++tt) {
#pragma unroll
        for (int reg = 0; reg < 4; ++reg) {
            const int r = tt * 16 + gq * 4 + reg;
            const float2 ld = ws2[W2_LDP + r * 128 + n];
            const float zr = z[tt][0][reg] + cin.x;
            const float zi = z[tt][1][reg] + cin.y;
            const float xr = ld.x * zr - ld.y * zi;
            const float xi = ld.x * zi + ld.y * zr;
            union { __hip_bfloat162 h2; unsigned uu; } pk;
            pk.h2 = __float22bfloat162_rn(make_float2(xr, xi));
            const int byte = (r * 512 + n * 4) ^ ((r & 7) << 4);
            *(unsigned*)((char*)lds + byte) = pk.uu;
        }
    }
    __syncthreads();

    // GEMM3: y[t][p]; wave w owns p-tile w, all t
    f32x4 yac[4];
#pragma unroll
    for (int i = 0; i < 4; ++i) yac[i] = (f32x4)0.f;
    __builtin_amdgcn_s_setprio(1);
#pragma unroll
    for (int ks = 0; ks < 8; ++ks) {
        const short8v bfrg = cc8[(w * 8 + ks) * 64 + lane];
#pragma unroll
        for (int tt = 0; tt < 4; ++tt) {
            const int t = tt * 16 + tl;
            const int byte = (t * 512 + (ks * 32 + gq * 8) * 2) ^ ((t & 7) << 4);
            const short8v a = *(const short8v*)((const char*)lds + byte);
            yac[tt] = __builtin_amdgcn_mfma_f32_16x16x32_bf16(a, bfrg, yac[tt], 0, 0, 0);
        }
    }
    __builtin_amdgcn_s_setprio(0);
    const int p = w * 16 + tl;
    float* yrow = y + (size_t)(b * 8192 + c * LCH) * 128;
#pragma unroll
    for (int tt = 0; tt < 4; ++tt) {
#pragma unroll
        for (int reg = 0; reg < 4; ++reg) {
            const int t = tt * 16 + gq * 4 + reg;
            yrow[t * 128 + p] = yac[tt][reg];
        }
    }
}

extern "C" void kernel_launch(void* const* d_in, const int* in_sizes, int n_in,
                              void* d_out, int out_size, void* d_ws, size_t ws_size,
                              hipStream_t stream) {
    const float* u     = (const float*)d_in[0];
    const float* lp    = (const float*)d_in[1];
    const float* bp    = (const float*)d_in[2];
    const float* cp    = (const float*)d_in[3];
    const float* delta = (const float*)d_in[4];
    float* y  = (float*)d_out;
    float2* ws2 = (float2*)d_ws;
    unsigned short* wpack  = (unsigned short*)((char*)d_ws + WS_WPACK_BYTE);
    unsigned short* ccpack = (unsigned short*)((char*)d_ws + WS_CCPACK_BYTE);

    k0_all  <<<192, 512, 0, stream>>>(lp, bp, cp, delta, ws2, wpack, ccpack);
    k1_end  <<<NCHUNKS, 512, 0, stream>>>(u, ws2, wpack);
    k2_carry<<<8, 256, 0, stream>>>(ws2);
    k3_main <<<NCHUNKS, 512, 0, stream>>>(u, ws2, wpack, ccpack, y);
}

// Round 12
// 84.317 us; speedup vs baseline: 6.6525x; 1.1605x over previous
//
#include <hip/hip_runtime.h>
#include <hip/hip_bf16.h>

// Problem: B=16, T=8192, M=P=128, N2=128. Chunks: L=128, 64/batch, 1024 total.
// R12: single-u-pass split. k3a = GEMM1 + scale -> store bf16 bus to global + E.
// k3b = load bus fragments from global -> tri-cumsum -> x -> GEMM3 -> y.
// Falls back to the R4-proven k1/k3 pair if ws_size can't hold the 67 MB bus.
#define LCH 128
#define NCH 64
#define NCHUNKS 1024

typedef __attribute__((ext_vector_type(8))) short short8v;
typedef __attribute__((ext_vector_type(4))) short short4v;
typedef __attribute__((ext_vector_type(4))) float f32x4;

// ws layout: float2 region (R4-proven offsets), packs, then bus.
#define W2_LDINV 0          // [128 r][128 n]  Ld^{-(r+1)}   (float2 idx)
#define W2_LDP   16384      // [128 r][128 n]  Ld^{r+1}
#define W2_E     32768      // [1024 g][128 n]
#define W2_CIN   163840     // [1024 g][128 n]
#define WS_WPACK_BYTE  2359296              // 32768 bf16: [ntile16][ks4][lane64][j8]
#define WS_CCPACK_BYTE (2359296 + 65536)    // 32768 bf16: [ptile8][ks8][lane64][j8]
#define WS_BUS_BYTE    (2359296 + 131072)   // 1024 chunks x 64 KB bf16 bus
#define WS_NEED ((size_t)WS_BUS_BYTE + (size_t)NCHUNKS * 65536)

// bus layout (LDS and global, byte-identical): byte(s,n') = (s>>3)*4096 + n'*16 + (s&7)*2
#define BUS_BYTE(s, np) ((((s) >> 3) * 4096) + ((np) * 16) + (((s) & 7) * 2))

__device__ inline unsigned short f2bf(float f) {
    union { __hip_bfloat16 h; unsigned short u; } v;
    v.h = __float2bfloat16(f);
    return v.u;
}
__device__ inline short4v pack4(float a, float b, float c, float d) {
    union { __hip_bfloat162 h2[2]; short4v s4; } pk;
    pk.h2[0] = __float22bfloat162_rn(make_float2(a, b));
    pk.h2[1] = __float22bfloat162_rn(make_float2(c, d));
    return pk.s4;
}

// ---------------- k0a: power tables (f64 exact) ----------------
__global__ void k0_pows(const float* __restrict__ lp, const float* __restrict__ delta,
                        float2* __restrict__ ws2) {
    const int r = blockIdx.x;          // 0..127
    const int tid = threadIdx.x;       // 0..255
    const int n = tid & 127;
    const double d = (double)delta[0];
    const double lre = -exp((double)lp[n]);
    const double lim = (double)lp[128 + n];
    const double kk = (double)(r + 1) * d;
    if (tid < 128) {
        const double mag = exp(-lre * kk);
        ws2[W2_LDINV + r * 128 + n] = make_float2((float)(mag * cos(lim * kk)),
                                                  (float)(-mag * sin(lim * kk)));
    } else {
        const double mag = exp(lre * kk);
        ws2[W2_LDP + r * 128 + n] = make_float2((float)(mag * cos(lim * kk)),
                                                (float)(mag * sin(lim * kk)));
    }
}

// ---------------- k0b: pack W = Bd^T as B-fragments ----------------
__global__ void k0_wpack(const float* __restrict__ lp, const float* __restrict__ bp,
                         const float* __restrict__ delta, unsigned short* __restrict__ wpack) {
    const int gid = blockIdx.x * 512 + threadIdx.x;    // 0..32767
    const int j = gid & 7;
    const int lane = (gid >> 3) & 63;
    const int ks = (gid >> 9) & 3;
    const int ntile = gid >> 11;
    const int np = ntile * 16 + (lane & 15);
    const int m = ks * 32 + ((lane >> 4) & 3) * 8 + j;
    const int n = np & 127;
    const double d = (double)delta[0];
    const double lre = -exp((double)lp[n]);
    const double lim = (double)lp[128 + n];
    const double er = exp(lre * d);
    const double ldr = er * cos(lim * d), ldi = er * sin(lim * d);
    const double nr = ldr - 1.0, ni = ldi;
    const double den = lre * lre + lim * lim;
    const double cr = (nr * lre + ni * lim) / den;
    const double ci = (ni * lre - nr * lim) / den;
    const double br = (double)bp[n * 128 + m];
    const double bi = (double)bp[16384 + n * 128 + m];
    const double v = (np < 128) ? (cr * br - ci * bi) : (cr * bi + ci * br);
    wpack[gid] = f2bf((float)v);
}

// ---------------- k0c: pack CC (K=256, re/im interleaved along k) ----------------
__global__ void k0_cpack(const float* __restrict__ cp, unsigned short* __restrict__ ccpack) {
    const int gid = blockIdx.x * 512 + threadIdx.x;    // 0..32767
    const int j = gid & 7;
    const int lane = (gid >> 3) & 63;
    const int ks = (gid >> 9) & 7;
    const int ptile = gid >> 12;
    const int p = ptile * 16 + (lane & 15);
    const int k = ks * 32 + ((lane >> 4) & 3) * 8 + j;
    const int n = k >> 1;
    const float v = ((k & 1) == 0) ? 2.0f * cp[p * 128 + n] : -2.0f * cp[16384 + p * 128 + n];
    ccpack[gid] = f2bf(v);
}

// ---------------- shared helper: stage u chunk -> LDS bf16 [t][m], XOR swizzle ----------------
__device__ inline void stage_u(const float* __restrict__ uchunk, unsigned short* lds_u) {
    const float4* uf = (const float4*)uchunk;
    const int tid = threadIdx.x;
#pragma unroll
    for (int it = 0; it < 8; ++it) {
        const int f4 = it * 512 + tid;
        const float4 v = uf[f4];
        const int t = f4 >> 5;
        const int m = (f4 & 31) * 4;
        const int byte = (t * 256 + m * 2) ^ ((t & 7) << 4);
        *(short4v*)((char*)lds_u + byte) = pack4(v.x, v.y, v.z, v.w);
    }
}

// ================= k3a: stage -> GEMM1(2 halves) -> scale -> bus global store + E =================
__global__ __launch_bounds__(512, 6) void k3a_bus(const float* __restrict__ u,
                                                  float2* __restrict__ ws2,
                                                  const unsigned short* __restrict__ wpack,
                                                  char* __restrict__ busg) {
    __shared__ unsigned short lds_u[16384];   // 32 KB
    const int tid = threadIdx.x;
    const int lane = tid & 63;
    const int w = tid >> 6;
    const int tl = lane & 15;
    const int gq = (lane >> 4) & 3;
    const int g = blockIdx.x;
    const int b = g >> 6;
    const int c = g & 63;
    const int n = w * 16 + tl;
    const short8v* wp = (const short8v*)wpack;
    char* busc = busg + (size_t)g * 65536;

    stage_u(u + (size_t)(b * 8192 + c * 128) * 128, lds_u);
    __syncthreads();

    float er = 0.f, ei = 0.f;
#pragma unroll
    for (int h = 0; h < 2; ++h) {
        f32x4 acc[4][2];
#pragma unroll
        for (int i = 0; i < 4; ++i) { acc[i][0] = (f32x4)0.f; acc[i][1] = (f32x4)0.f; }
        __builtin_amdgcn_s_setprio(1);
#pragma unroll
        for (int ks = 0; ks < 4; ++ks) {
            const short8v b0 = wp[(w * 4 + ks) * 64 + lane];
            const short8v b1 = wp[((8 + w) * 4 + ks) * 64 + lane];
#pragma unroll
            for (int tt2 = 0; tt2 < 4; ++tt2) {
                const int t = (h * 4 + tt2) * 16 + tl;
                const int byte = (t * 256 + (ks * 32 + gq * 8) * 2) ^ ((t & 7) << 4);
                const short8v a = *(const short8v*)((const char*)lds_u + byte);
                acc[tt2][0] = __builtin_amdgcn_mfma_f32_16x16x32_bf16(a, b0, acc[tt2][0], 0, 0, 0);
                acc[tt2][1] = __builtin_amdgcn_mfma_f32_16x16x32_bf16(a, b1, acc[tt2][1], 0, 0, 0);
            }
        }
        __builtin_amdgcn_s_setprio(0);
        __builtin_amdgcn_sched_barrier(0);
#pragma unroll
        for (int tt2 = 0; tt2 < 4; ++tt2) {
            float vr[4], vi[4];
#pragma unroll
            for (int reg = 0; reg < 4; ++reg) {
                const int r = (h * 4 + tt2) * 16 + gq * 4 + reg;
                const float2 li = ws2[W2_LDINV + r * 128 + n];
                const float br = acc[tt2][0][reg], bi = acc[tt2][1][reg];
                vr[reg] = li.x * br - li.y * bi;
                vi[reg] = li.x * bi + li.y * br;
                er += vr[reg];
                ei += vi[reg];
            }
            const int s0 = (h * 4 + tt2) * 16 + gq * 4;
            const int rowr = w * 16 + tl;
            const int rowi = 128 + rowr;
            *(short4v*)(busc + BUS_BYTE(s0, rowr)) = pack4(vr[0], vr[1], vr[2], vr[3]);
            *(short4v*)(busc + BUS_BYTE(s0, rowi)) = pack4(vi[0], vi[1], vi[2], vi[3]);
        }
        __builtin_amdgcn_sched_barrier(0);
    }
    // E[g][n] = Ld^128 * sum_s (Ldinv[s] (.) Bu[s,n])   (f32, pre-bf16-round — as R4 k1)
    er += __shfl_xor(er, 16); ei += __shfl_xor(ei, 16);
    er += __shfl_xor(er, 32); ei += __shfl_xor(ei, 32);
    const float2 ld = ws2[W2_LDP + 127 * 128 + n];
    if (lane < 16) {
        ws2[W2_E + g * 128 + n] = make_float2(ld.x * er - ld.y * ei,
                                              ld.x * ei + ld.y * er);
    }
}

// ---------------- k2: chunk-level scan -> carry-in (R4-proven) ----------------
__global__ void k2_carry(float2* __restrict__ ws2) {
    const int idx = blockIdx.x * 256 + threadIdx.x;   // 0..2047
    const int b = idx >> 7;
    const int n = idx & 127;
    const float2 l = ws2[W2_LDP + 127 * 128 + n];
    float cr = 0.f, ci = 0.f;
    for (int c = 0; c < NCH; ++c) {
        const int o = (b * NCH + c) * 128 + n;
        ws2[W2_CIN + o] = make_float2(cr, ci);
        const float2 e = ws2[W2_E + o];
        const float nr = fmaf(l.x, cr, fmaf(-l.y, ci, e.x));
        const float ni = fmaf(l.x, ci, fmaf(l.y, cr, e.y));
        cr = nr; ci = ni;
    }
}

// ================= k3b: bus fragments from global -> tri-cumsum -> x -> GEMM3 -> y =================
__global__ __launch_bounds__(512, 4) void k3b_out(const float2* __restrict__ ws2,
                                                  const char* __restrict__ busg,
                                                  const unsigned short* __restrict__ ccpack,
                                                  float* __restrict__ y) {
    __shared__ unsigned short lds[32768];     // 64 KB: x tile
    const int tid = threadIdx.x;
    const int lane = tid & 63;
    const int w = tid >> 6;
    const int tl = lane & 15;
    const int gq = (lane >> 4) & 3;
    const int g = blockIdx.x;
    const int b = g >> 6;
    const int c = g & 63;
    const int n = w * 16 + tl;
    const short8v* cc8 = (const short8v*)ccpack;
    const char* busc = busg + (size_t)g * 65536;

    // GEMM2: z = T_lower_ones x Bus (B-fragments direct from global, coalesced 16B/lane)
    short8v ONES, D0, D1;
#pragma unroll
    for (int j = 0; j < 8; ++j) {
        const int sl = gq * 8 + j;
        ONES[j] = (short)0x3F80;
        D0[j] = (sl <= tl) ? (short)0x3F80 : (short)0;
        D1[j] = (sl <= tl + 16) ? (short)0x3F80 : (short)0;
    }
    f32x4 z[8][2];
#pragma unroll
    for (int i = 0; i < 8; ++i) { z[i][0] = (f32x4)0.f; z[i][1] = (f32x4)0.f; }
#pragma unroll
    for (int ks = 0; ks < 4; ++ks) {
        const int sb = ks * 32 + gq * 8;                 // (sb&7)==0
        const int rowr = w * 16 + tl;
        const int rowi = 128 + rowr;
        const short8v b0 = *(const short8v*)(busc + BUS_BYTE(sb, rowr));
        const short8v b1 = *(const short8v*)(busc + BUS_BYTE(sb, rowi));
#pragma unroll
        for (int tt = 0; tt < 8; ++tt) {
            if (tt < 2 * ks) continue;                   // zero block
            const short8v a = (tt == 2 * ks) ? D0 : ((tt == 2 * ks + 1) ? D1 : ONES);
            z[tt][0] = __builtin_amdgcn_mfma_f32_16x16x32_bf16(a, b0, z[tt][0], 0, 0, 0);
            z[tt][1] = __builtin_amdgcn_mfma_f32_16x16x32_bf16(a, b1, z[tt][1], 0, 0, 0);
        }
    }

    // x[t][k''] = Ldp[t] (.) (z + carry), re/im interleaved along k''=2n+parity
    const float2 cin = ws2[W2_CIN + g * 128 + n];
#pragma unroll
    for (int tt = 0; tt < 8; ++tt) {
#pragma unroll
        for (int reg = 0; reg < 4; ++reg) {
            const int r = tt * 16 + gq * 4 + reg;
            const float2 ld = ws2[W2_LDP + r * 128 + n];
            const float zr = z[tt][0][reg] + cin.x;
            const float zi = z[tt][1][reg] + cin.y;
            const float xr = ld.x * zr - ld.y * zi;
            const float xi = ld.x * zi + ld.y * zr;
            union { __hip_bfloat162 h2; unsigned uu; } pk;
            pk.h2 = __float22bfloat162_rn(make_float2(xr, xi));
            const int byte = (r * 512 + n * 4) ^ ((r & 7) << 4);
            *(unsigned*)((char*)lds + byte) = pk.uu;
        }
    }
    __syncthreads();

    // GEMM3: y[t][p]; wave w owns p-tile w, all t
    f32x4 yac[8];
#pragma unroll
    for (int i = 0; i < 8; ++i) yac[i] = (f32x4)0.f;
    __builtin_amdgcn_s_setprio(1);
#pragma unroll
    for (int ks = 0; ks < 8; ++ks) {
        const short8v bfrg = cc8[(w * 8 + ks) * 64 + lane];
#pragma unroll
        for (int tt = 0; tt < 8; ++tt) {
            const int t = tt * 16 + tl;
            const int byte = (t * 512 + (ks * 32 + gq * 8) * 2) ^ ((t & 7) << 4);
            const short8v a = *(const short8v*)((const char*)lds + byte);
            yac[tt] = __builtin_amdgcn_mfma_f32_16x16x32_bf16(a, bfrg, yac[tt], 0, 0, 0);
        }
    }
    __builtin_amdgcn_s_setprio(0);
    const int p = w * 16 + tl;
    float* yrow = y + (size_t)(b * 8192 + c * 128) * 128;
#pragma unroll
    for (int tt = 0; tt < 8; ++tt) {
#pragma unroll
        for (int reg = 0; reg < 4; ++reg) {
            const int t = tt * 16 + gq * 4 + reg;
            yrow[t * 128 + p] = yac[tt][reg];
        }
    }
}

// ================= fallback path: R4-proven k1 + k3 (used if ws too small) =================
__global__ __launch_bounds__(512, 4) void k1_end(const float* __restrict__ u,
                                                 float2* __restrict__ ws2,
                                                 const unsigned short* __restrict__ wpack) {
    __shared__ unsigned short lds_u[16384];   // 32 KB
    const int tid = threadIdx.x;
    const int lane = tid & 63;
    const int w = tid >> 6;
    const int tl = lane & 15;
    const int gq = (lane >> 4) & 3;
    const int g = blockIdx.x;
    const int b = g >> 6;
    const int c = g & 63;
    const int n = w * 16 + tl;
    stage_u(u + (size_t)(b * 8192 + c * 128) * 128, lds_u);
    __syncthreads();
    const short8v* wp = (const short8v*)wpack;
    float er = 0.f, ei = 0.f;
#pragma unroll
    for (int h = 0; h < 2; ++h) {
        f32x4 acc[4][2];
#pragma unroll
        for (int i = 0; i < 4; ++i) { acc[i][0] = (f32x4)0.f; acc[i][1] = (f32x4)0.f; }
        __builtin_amdgcn_s_setprio(1);
#pragma unroll
        for (int ks = 0; ks < 4; ++ks) {
            const short8v b0 = wp[(w * 4 + ks) * 64 + lane];
            const short8v b1 = wp[((8 + w) * 4 + ks) * 64 + lane];
#pragma unroll
            for (int tt2 = 0; tt2 < 4; ++tt2) {
                const int t = (h * 4 + tt2) * 16 + tl;
                const int byte = (t * 256 + (ks * 32 + gq * 8) * 2) ^ ((t & 7) << 4);
                const short8v a = *(const short8v*)((const char*)lds_u + byte);
                acc[tt2][0] = __builtin_amdgcn_mfma_f32_16x16x32_bf16(a, b0, acc[tt2][0], 0, 0, 0);
                acc[tt2][1] = __builtin_amdgcn_mfma_f32_16x16x32_bf16(a, b1, acc[tt2][1], 0, 0, 0);
            }
        }
        __builtin_amdgcn_s_setprio(0);
        __builtin_amdgcn_sched_barrier(0);
#pragma unroll
        for (int tt2 = 0; tt2 < 4; ++tt2) {
#pragma unroll
            for (int reg = 0; reg < 4; ++reg) {
                const int r = (h * 4 + tt2) * 16 + gq * 4 + reg;
                const float2 li = ws2[W2_LDINV + r * 128 + n];
                const float br = acc[tt2][0][reg], bi = acc[tt2][1][reg];
                er += li.x * br - li.y * bi;
                ei += li.x * bi + li.y * br;
            }
        }
        __builtin_amdgcn_sched_barrier(0);
    }
    er += __shfl_xor(er, 16); ei += __shfl_xor(ei, 16);
    er += __shfl_xor(er, 32); ei += __shfl_xor(ei, 32);
    const float2 ld = ws2[W2_LDP + 127 * 128 + n];
    if (lane < 16) {
        ws2[W2_E + g * 128 + n] = make_float2(ld.x * er - ld.y * ei,
                                              ld.x * ei + ld.y * er);
    }
}

__global__ __launch_bounds__(512, 4) void k3_main(const float* __restrict__ u,
                                                  const float2* __restrict__ ws2,
                                                  const unsigned short* __restrict__ wpack,
                                                  const unsigned short* __restrict__ ccpack,
                                                  float* __restrict__ y) {
    __shared__ unsigned short lds[32768];     // 64 KB
    const int tid = threadIdx.x;
    const int lane = tid & 63;
    const int w = tid >> 6;
    const int tl = lane & 15;
    const int gq = (lane >> 4) & 3;
    const int g = blockIdx.x;
    const int b = g >> 6;
    const int c = g & 63;
    const int n = w * 16 + tl;
    const short8v* wp = (const short8v*)wpack;
    const short8v* cc8 = (const short8v*)ccpack;

    stage_u(u + (size_t)(b * 8192 + c * 128) * 128, lds);
    __syncthreads();
#pragma unroll
    for (int hh = 0; hh < 2; ++hh) {
        const int h = 1 - hh;
        f32x4 acc[4][2];
#pragma unroll
        for (int i = 0; i < 4; ++i) { acc[i][0] = (f32x4)0.f; acc[i][1] = (f32x4)0.f; }
        __builtin_amdgcn_s_setprio(1);
#pragma unroll
        for (int ks = 0; ks < 4; ++ks) {
            const short8v b0 = wp[(w * 4 + ks) * 64 + lane];
            const short8v b1 = wp[((8 + w) * 4 + ks) * 64 + lane];
#pragma unroll
            for (int tt2 = 0; tt2 < 4; ++tt2) {
                const int t = (h * 4 + tt2) * 16 + tl;
                const int byte = (t * 256 + (ks * 32 + gq * 8) * 2) ^ ((t & 7) << 4);
                const short8v a = *(const short8v*)((const char*)lds + byte);
                acc[tt2][0] = __builtin_amdgcn_mfma_f32_16x16x32_bf16(a, b0, acc[tt2][0], 0, 0, 0);
                acc[tt2][1] = __builtin_amdgcn_mfma_f32_16x16x32_bf16(a, b1, acc[tt2][1], 0, 0, 0);
            }
        }
        __builtin_amdgcn_s_setprio(0);
        __builtin_amdgcn_sched_barrier(0);
        if (h == 0) __syncthreads();
#pragma unroll
        for (int tt2 = 0; tt2 < 4; ++tt2) {
            float vr[4], vi[4];
#pragma unroll
            for (int reg = 0; reg < 4; ++reg) {
                const int r = (h * 4 + tt2) * 16 + gq * 4 + reg;
                const float2 li = ws2[W2_LDINV + r * 128 + n];
                const float br = acc[tt2][0][reg], bi = acc[tt2][1][reg];
                vr[reg] = li.x * br - li.y * bi;
                vi[reg] = li.x * bi + li.y * br;
            }
            const int s0 = (h * 4 + tt2) * 16 + gq * 4;
            const int rowr = w * 16 + tl;
            const int rowi = 128 + rowr;
            *(short4v*)((char*)lds + BUS_BYTE(s0, rowr)) = pack4(vr[0], vr[1], vr[2], vr[3]);
            *(short4v*)((char*)lds + BUS_BYTE(s0, rowi)) = pack4(vi[0], vi[1], vi[2], vi[3]);
        }
        __builtin_amdgcn_sched_barrier(0);
    }
    short8v ONES, D0, D1;
#pragma unroll
    for (int j = 0; j < 8; ++j) {
        const int sl = gq * 8 + j;
        ONES[j] = (short)0x3F80;
        D0[j] = (sl <= tl) ? (short)0x3F80 : (short)0;
        D1[j] = (sl <= tl + 16) ? (short)0x3F80 : (short)0;
    }
    f32x4 z[8][2];
#pragma unroll
    for (int i = 0; i < 8; ++i) { z[i][0] = (f32x4)0.f; z[i][1] = (f32x4)0.f; }
#pragma unroll
    for (int ks = 0; ks < 4; ++ks) {
        const int sb = ks * 32 + gq * 8;
        const int rowr = w * 16 + tl;
        const int rowi = 128 + rowr;
        const short8v b0 = *(const short8v*)((const char*)lds + BUS_BYTE(sb, rowr));
        const short8v b1 = *(const short8v*)((const char*)lds + BUS_BYTE(sb, rowi));
#pragma unroll
        for (int tt = 0; tt < 8; ++tt) {
            if (tt < 2 * ks) continue;
            const short8v a = (tt == 2 * ks) ? D0 : ((tt == 2 * ks + 1) ? D1 : ONES);
            z[tt][0] = __builtin_amdgcn_mfma_f32_16x16x32_bf16(a, b0, z[tt][0], 0, 0, 0);
            z[tt][1] = __builtin_amdgcn_mfma_f32_16x16x32_bf16(a, b1, z[tt][1], 0, 0, 0);
        }
    }
    __syncthreads();
    const float2 cin = ws2[W2_CIN + g * 128 + n];
#pragma unroll
    for (int tt = 0; tt < 8; ++tt) {
#pragma unroll
        for (int reg = 0; reg < 4; ++reg) {
            const int r = tt * 16 + gq * 4 + reg;
            const float2 ld = ws2[W2_LDP + r * 128 + n];
            const float zr = z[tt][0][reg] + cin.x;
            const float zi = z[tt][1][reg] + cin.y;
            const float xr = ld.x * zr - ld.y * zi;
            const float xi = ld.x * zi + ld.y * zr;
            union { __hip_bfloat162 h2; unsigned uu; } pk;
            pk.h2 = __float22bfloat162_rn(make_float2(xr, xi));
            const int byte = (r * 512 + n * 4) ^ ((r & 7) << 4);
            *(unsigned*)((char*)lds + byte) = pk.uu;
        }
    }
    __syncthreads();
    f32x4 yac[8];
#pragma unroll
    for (int i = 0; i < 8; ++i) yac[i] = (f32x4)0.f;
    __builtin_amdgcn_s_setprio(1);
#pragma unroll
    for (int ks = 0; ks < 8; ++ks) {
        const short8v bfrg = cc8[(w * 8 + ks) * 64 + lane];
#pragma unroll
        for (int tt = 0; tt < 8; ++tt) {
            const int t = tt * 16 + tl;
            const int byte = (t * 512 + (ks * 32 + gq * 8) * 2) ^ ((t & 7) << 4);
            const short8v a = *(const short8v*)((const char*)lds + byte);
            yac[tt] = __builtin_amdgcn_mfma_f32_16x16x32_bf16(a, bfrg, yac[tt], 0, 0, 0);
        }
    }
    __builtin_amdgcn_s_setprio(0);
    const int p = w * 16 + tl;
    float* yrow = y + (size_t)(b * 8192 + c * 128) * 128;
#pragma unroll
    for (int tt = 0; tt < 8; ++tt) {
#pragma unroll
        for (int reg = 0; reg < 4; ++reg) {
            const int t = tt * 16 + gq * 4 + reg;
            yrow[t * 128 + p] = yac[tt][reg];
        }
    }
}

extern "C" void kernel_launch(void* const* d_in, const int* in_sizes, int n_in,
                              void* d_out, int out_size, void* d_ws, size_t ws_size,
                              hipStream_t stream) {
    const float* u     = (const float*)d_in[0];
    const float* lp    = (const float*)d_in[1];
    const float* bp    = (const float*)d_in[2];
    const float* cp    = (const float*)d_in[3];
    const float* delta = (const float*)d_in[4];
    float* y  = (float*)d_out;
    float2* ws2 = (float2*)d_ws;
    unsigned short* wpack  = (unsigned short*)((char*)d_ws + WS_WPACK_BYTE);
    unsigned short* ccpack = (unsigned short*)((char*)d_ws + WS_CCPACK_BYTE);
    char* busg = (char*)d_ws + WS_BUS_BYTE;

    k0_pows <<<128, 256, 0, stream>>>(lp, delta, ws2);
    k0_wpack<<<64, 512, 0, stream>>>(lp, bp, delta, wpack);
    k0_cpack<<<64, 512, 0, stream>>>(cp, ccpack);

    if (ws_size >= WS_NEED) {
        // single-u-pass split path
        k3a_bus <<<NCHUNKS, 512, 0, stream>>>(u, ws2, wpack, busg);
        k2_carry<<<8, 256, 0, stream>>>(ws2);
        k3b_out <<<NCHUNKS, 512, 0, stream>>>(ws2, busg, ccpack, y);
    } else {
        // R4-proven fallback (u read twice)
        k1_end  <<<NCHUNKS, 512, 0, stream>>>(u, ws2, wpack);
        k2_carry<<<8, 256, 0, stream>>>(ws2);
        k3_main <<<NCHUNKS, 512, 0, stream>>>(u, ws2, wpack, ccpack, y);
    }
}